// Round 1
// baseline (1613.892 us; speedup 1.0000x reference)
//
#include <hip/hip_runtime.h>

#define EPSF 1e-8f

constexpr int D0   = 128;   // input dim
constexpr int R    = 256;   // random features
constexpr int D1   = 64;    // output dim
constexpr int ROWS = 32;    // rows per workgroup
constexpr int KC1  = 4;     // phase-1 K chunk
constexpr int KC2  = 16;    // phase-2 K chunk
constexpr int NT   = 256;   // threads per WG

__device__ __forceinline__ void ld4(float* dst, const float* src) {
    float4 v = *(const float4*)src;
    dst[0] = v.x; dst[1] = v.y; dst[2] = v.z; dst[3] = v.w;
}

__global__ __launch_bounds__(NT, 2)
void dgp_fused(const float* __restrict__ X,
               const int*   __restrict__ Xidx,
               const float* __restrict__ W1mu,
               const float* __restrict__ W1var,
               const float* __restrict__ W2mu,
               const float* __restrict__ W2var,
               float* __restrict__ accM,   // [U*64] -> will become means
               float* __restrict__ accP)   // [U*64] -> will become vars
{
    // LDS: 32*257*4*2 + 4*32*4 + 2*4*256*4 = 74496 B  -> 2 WG/CU
    __shared__ float M1s[ROWS][R + 1];
    __shared__ float V1s[ROWS][R + 1];
    __shared__ float Xs[KC1][ROWS];
    __shared__ float Wst[2][KC1][R];   // phase-2 reuses this as [2][KC2][D1]

    const int t    = threadIdx.x;
    const int row0 = blockIdx.x * ROWS;

    // ---------------- Phase 1: m1 = X@W1mu^T, v1 = X^2@W1var^T + RF ReLU ----
    const int i = t >> 4;       // 0..15 : row group (2 rows)
    const int j = t & 15;       // 0..15 : rf group (16 rfs)
    const int jrot = j >> 1;    // swizzle rotation for this thread

    float accm[2][16];
    float accv[2][16];
    #pragma unroll
    for (int r = 0; r < 2; ++r)
        #pragma unroll
        for (int q = 0; q < 16; ++q) { accm[r][q] = 0.f; accv[r][q] = 0.f; }

    const float4* W1mu4  = (const float4*)W1mu;
    const float4* W1var4 = (const float4*)W1var;
    const float4* X4     = (const float4*)X;

    // staging swizzle: rf = t -> column (16B sub-block rotated by sj>>1)
    const int sj = t >> 4, sq = (t >> 2) & 3, se = t & 3;
    const int scol = (sj << 4) + (((sq + (sj >> 1)) & 3) << 2) + se;

    for (int c = 0; c < D0 / KC1; ++c) {   // 32 chunks of K=4
        __syncthreads();
        // stage W1 chunk transposed + swizzled: Wst[a][kl][swz(rf)]
        float4 wm = W1mu4[(size_t)t * (D0 / 4) + c];
        float4 wv = W1var4[(size_t)t * (D0 / 4) + c];
        Wst[0][0][scol] = wm.x; Wst[0][1][scol] = wm.y;
        Wst[0][2][scol] = wm.z; Wst[0][3][scol] = wm.w;
        Wst[1][0][scol] = wv.x; Wst[1][1][scol] = wv.y;
        Wst[1][2][scol] = wv.z; Wst[1][3][scol] = wv.w;
        if (t < ROWS) {
            float4 xv = X4[(size_t)(row0 + t) * (D0 / 4) + c];
            Xs[0][t] = xv.x; Xs[1][t] = xv.y; Xs[2][t] = xv.z; Xs[3][t] = xv.w;
        }
        __syncthreads();

        #pragma unroll
        for (int k = 0; k < KC1; ++k) {
            const float4* wr = (const float4*)&Wst[0][k][0];
            const float4* vr = (const float4*)&Wst[1][k][0];
            float wa[16], wb[16];
            #pragma unroll
            for (int q = 0; q < 4; ++q) {
                int pos = (q + jrot) & 3;   // de-swizzle
                *(float4*)&wa[q * 4] = wr[j * 4 + pos];
                *(float4*)&wb[q * 4] = vr[j * 4 + pos];
            }
            #pragma unroll
            for (int r = 0; r < 2; ++r) {
                float x  = Xs[k][(i << 1) + r];
                float x2 = x * x;
                #pragma unroll
                for (int q = 0; q < 16; ++q) {
                    accm[r][q] = fmaf(x,  wa[q], accm[r][q]);
                    accv[r][q] = fmaf(x2, wb[q], accv[r][q]);
                }
            }
        }
    }

    // RF-ReLU epilogue, write m1/v1 tiles to LDS
    const float SCALE  = 0.08838834764831845f;  // sqrt(2/256)
    const float SCALE2 = 0.0078125f;            // 2/256
    #pragma unroll
    for (int r = 0; r < 2; ++r) {
        int row = (i << 1) + r;
        #pragma unroll
        for (int q = 0; q < 16; ++q) {
            int rf = j * 16 + q;
            float om  = accm[r][q];
            bool pos  = om > 0.f;
            M1s[row][rf] = pos ? SCALE * om : 0.f;
            V1s[row][rf] = pos ? SCALE2 * accv[r][q] : 0.f;
        }
    }

    // ---------------- Phase 2: layer-2 moment GEMMs ------------------------
    const int row2 = t >> 3;   // 0..31
    const int jg   = t & 7;    // d1 group: d1 = jg*8 + q
    float m2[8], v2[8];
    #pragma unroll
    for (int q = 0; q < 8; ++q) { m2[q] = 0.f; v2[q] = 0.f; }

    float (*W2s)[KC2][D1] = (float (*)[KC2][D1])Wst;  // reuse 8KB buffer
    const float4* W2mu4  = (const float4*)W2mu;
    const float4* W2var4 = (const float4*)W2var;
    const int d1s = t >> 2;    // 0..63
    const int e   = t & 3;

    for (int c = 0; c < R / KC2; ++c) {   // 16 chunks of K=16
        __syncthreads();   // also covers M1s/V1s visibility & Wst reuse
        float4 wm = W2mu4[(size_t)d1s * (R / 4) + c * 4 + e];
        float4 wv = W2var4[(size_t)d1s * (R / 4) + c * 4 + e];
        W2s[0][e * 4 + 0][d1s] = wm.x; W2s[0][e * 4 + 1][d1s] = wm.y;
        W2s[0][e * 4 + 2][d1s] = wm.z; W2s[0][e * 4 + 3][d1s] = wm.w;
        W2s[1][e * 4 + 0][d1s] = wv.x; W2s[1][e * 4 + 1][d1s] = wv.y;
        W2s[1][e * 4 + 2][d1s] = wv.z; W2s[1][e * 4 + 3][d1s] = wv.w;
        __syncthreads();

        #pragma unroll
        for (int k = 0; k < KC2; ++k) {
            float m1  = M1s[row2][c * KC2 + k];
            float v1  = V1s[row2][c * KC2 + k];
            float tsum = fmaf(m1, m1, v1);   // v1 + m1^2
            float wa[8], wb[8];
            ld4(&wa[0], &W2s[0][k][jg * 8]);
            ld4(&wa[4], &W2s[0][k][jg * 8 + 4]);
            ld4(&wb[0], &W2s[1][k][jg * 8]);
            ld4(&wb[4], &W2s[1][k][jg * 8 + 4]);
            #pragma unroll
            for (int q = 0; q < 8; ++q) {
                m2[q] = fmaf(m1, wa[q], m2[q]);
                v2[q] = fmaf(tsum, wb[q], v2[q]);
                v2[q] = fmaf(v1 * wa[q], wa[q], v2[q]);  // + v1*wmu^2
            }
        }
    }

    // ---------------- Phase 3: precision-weighted scatter ------------------
    const int gidx = Xidx[row0 + row2];
    float* aM = accM + (size_t)gidx * D1 + jg * 8;
    float* aP = accP + (size_t)gidx * D1 + jg * 8;
    #pragma unroll
    for (int q = 0; q < 8; ++q) {
        float p = 1.0f / (v2[q] + EPSF);
        atomicAdd(&aM[q], p * m2[q]);
        atomicAdd(&aP[q], p);
    }
}

__global__ void dgp_finalize(float* __restrict__ accM,
                             float* __restrict__ accP, int total)
{
    int idx = blockIdx.x * blockDim.x + threadIdx.x;
    if (idx < total) {
        float var = 1.0f / (accP[idx] + EPSF);   // p_sum = seg_sum + EPS
        accP[idx] = var;                         // embedd_vars
        accM[idx] = accM[idx] * var;             // embedd_means
    }
}

extern "C" void kernel_launch(void* const* d_in, const int* in_sizes, int n_in,
                              void* d_out, int out_size, void* d_ws, size_t ws_size,
                              hipStream_t stream)
{
    const float* X     = (const float*)d_in[0];
    const int*   Xidx  = (const int*)d_in[1];
    const float* W1mu  = (const float*)d_in[2];
    const float* W1var = (const float*)d_in[3];
    const float* W2mu  = (const float*)d_in[4];
    const float* W2var = (const float*)d_in[5];

    const int N = in_sizes[0] / D0;            // 262144
    const int U = out_size / (2 * D1);         // 50000
    float* out  = (float*)d_out;
    float* accM = out;                          // means region
    float* accP = out + (size_t)U * D1;         // vars region

    // harness does not re-poison between replays: re-zero accumulators
    hipMemsetAsync(d_out, 0, (size_t)out_size * sizeof(float), stream);

    dgp_fused<<<N / ROWS, NT, 0, stream>>>(X, Xidx, W1mu, W1var, W2mu, W2var,
                                           accM, accP);

    const int total = U * D1;
    dgp_finalize<<<(total + 255) / 256, 256, 0, stream>>>(accM, accP, total);
}

// Round 2
// 205.930 us; speedup vs baseline: 7.8371x; 7.8371x over previous
//
#include <hip/hip_runtime.h>

#define EPSF 1e-8f

constexpr int D0 = 128;   // input dim
constexpr int R  = 256;   // random features
constexpr int D1 = 64;    // output dim
constexpr int BM = 32;    // rows per block
constexpr int NT = 256;   // threads per block (4 waves)

typedef __attribute__((ext_vector_type(8))) short  bf16x8;
typedef __attribute__((ext_vector_type(4))) float  f32x4;

// ws layout (ushort elements):
//   [0]      w1mu  frags: 64 frags * 64 lanes * 8 = 32768
//   [32768]  w1var frags: 32768
//   [65536]  w2mu  frags: 32 frags * 64 lanes * 8 = 16384
//   [81920]  w2var frags: 16384
//   [98304]  w2mu2 frags: 16384            (total 114688 ushort = 224 KB)
constexpr int WS_W1VAR = 32768;
constexpr int WS_W2MU  = 65536;
constexpr int WS_W2VAR = 81920;
constexpr int WS_W2SQ  = 98304;

__device__ __forceinline__ ushort f2bf(float x) {
    uint32_t u = __builtin_bit_cast(uint32_t, x);
    u += 0x7FFFu + ((u >> 16) & 1u);          // round-to-nearest-even
    return (ushort)(u >> 16);
}

// --- pre-kernel: convert weights to bf16 in MFMA B-fragment order ----------
// B-frag for mfma_f32_16x16x32_bf16: lane l, elem j -> B[k][col],
//   col = (l&15), k = (l>>4)*8 + j  (within a 16-col x 32-k tile)
__global__ void convert_w(const float* __restrict__ W1mu,
                          const float* __restrict__ W1var,
                          const float* __restrict__ W2mu,
                          const float* __restrict__ W2var,
                          ushort* __restrict__ ws)
{
    int tid = blockIdx.x * 256 + threadIdx.x;
    if (tid < 8192) {                       // layer 1: 2 mats * 64 frags * 64 lanes
        int m    = tid >> 12;               // 0=mu 1=var
        int f    = (tid >> 6) & 63;         // frag = nt*4 + ks
        int lane = tid & 63;
        int nt = f >> 2, ks = f & 3;
        int col = nt * 16 + (lane & 15);    // rf index (W1 row)
        int k0  = ks * 32 + (lane >> 4) * 8;
        const float* src = (m ? W1var : W1mu) + (size_t)col * D0 + k0;
        ushort* dst = ws + (m ? WS_W1VAR : 0) + (size_t)(f * 64 + lane) * 8;
        #pragma unroll
        for (int j = 0; j < 8; ++j) dst[j] = f2bf(src[j]);
    } else if (tid < 8192 + 3 * 2048) {     // layer 2: 3 mats * 32 frags * 64 lanes
        int t2   = tid - 8192;
        int m    = t2 >> 11;                // 0=mu 1=var 2=mu^2
        int f    = (t2 >> 6) & 31;          // frag = nt*8 + ks
        int lane = t2 & 63;
        int nt = f >> 3, ks = f & 7;
        int col = nt * 16 + (lane & 15);    // d1 index (W2 row)
        int k0  = ks * 32 + (lane >> 4) * 8;
        const float* src = (m == 1 ? W2var : W2mu) + (size_t)col * R + k0;
        ushort* dst = ws + WS_W2MU + m * 16384 + (size_t)(f * 64 + lane) * 8;
        #pragma unroll
        for (int j = 0; j < 8; ++j) {
            float v = src[j];
            if (m == 2) v = v * v;
            dst[j] = f2bf(v);
        }
    }
}

// --- fused main kernel ------------------------------------------------------
__global__ __launch_bounds__(NT, 3)
void dgp_mfma(const float* __restrict__ X,
              const int*   __restrict__ Xidx,
              const ushort* __restrict__ ws,
              float* __restrict__ accM,
              float* __restrict__ accP)
{
    // 3 bf16 slabs [32][256], XOR-swizzled: 48 KB -> 3 blocks/CU
    __shared__ ushort M1s[BM * R];
    __shared__ ushort T1s[BM * R];
    __shared__ ushort V1s[BM * R];

    const int t    = threadIdx.x;
    const int lane = t & 63;
    const int w    = t >> 6;         // wave 0..3
    const int row0 = blockIdx.x * BM;
    const int lrow = lane & 15;      // A-row / C-col component
    const int lk   = lane >> 4;      // 0..3 (k-group / C-row group)

    // ---------------- Layer 1: m1 = X@W1mu^T, v1 = X^2@W1var^T -------------
    // wave w owns cols [w*64, w*64+64) (4 N-tiles), rows 0..31 (2 row-tiles)
    f32x4 accm[2][4], accv[2][4];
    #pragma unroll
    for (int rt = 0; rt < 2; ++rt)
        #pragma unroll
        for (int nt = 0; nt < 4; ++nt) {
            accm[rt][nt] = (f32x4)0.f;
            accv[rt][nt] = (f32x4)0.f;
        }

    #pragma unroll
    for (int ks = 0; ks < 4; ++ks) {
        bf16x8 xm[2], xs[2];
        #pragma unroll
        for (int rt = 0; rt < 2; ++rt) {
            const float* xp = X + (size_t)(row0 + rt * 16 + lrow) * D0 + ks * 32 + lk * 8;
            float4 a = *(const float4*)xp;
            float4 b = *(const float4*)(xp + 4);
            float v[8] = {a.x, a.y, a.z, a.w, b.x, b.y, b.z, b.w};
            #pragma unroll
            for (int j = 0; j < 8; ++j) {
                xm[rt][j] = (short)f2bf(v[j]);
                xs[rt][j] = (short)f2bf(v[j] * v[j]);
            }
        }
        #pragma unroll
        for (int nt = 0; nt < 4; ++nt) {
            int f = (w * 4 + nt) * 4 + ks;
            bf16x8 bmu = *(const bf16x8*)(ws + (size_t)(f * 64 + lane) * 8);
            bf16x8 bvr = *(const bf16x8*)(ws + WS_W1VAR + (size_t)(f * 64 + lane) * 8);
            #pragma unroll
            for (int rt = 0; rt < 2; ++rt) {
                accm[rt][nt] = __builtin_amdgcn_mfma_f32_16x16x32_bf16(xm[rt], bmu, accm[rt][nt], 0, 0, 0);
                accv[rt][nt] = __builtin_amdgcn_mfma_f32_16x16x32_bf16(xs[rt], bvr, accv[rt][nt], 0, 0, 0);
            }
        }
    }

    // RF-ReLU epilogue -> bf16 slabs (XOR-swizzled)
    const float SCALE  = 0.08838834764831845f;  // sqrt(2/256)
    const float SCALE2 = 0.0078125f;            // 2/256
    #pragma unroll
    for (int rt = 0; rt < 2; ++rt)
        #pragma unroll
        for (int nt = 0; nt < 4; ++nt) {
            int col = (w * 4 + nt) * 16 + lrow;     // rf index
            #pragma unroll
            for (int i = 0; i < 4; ++i) {
                int row = rt * 16 + lk * 4 + i;      // local row
                float om = accm[rt][nt][i];
                float ov = accv[rt][nt][i];
                float m1 = om > 0.f ? SCALE  * om : 0.f;
                float v1 = om > 0.f ? SCALE2 * ov : 0.f;
                float t1 = fmaf(m1, m1, v1);         // v1 + m1^2
                int idx = row * 256 + (col ^ ((row & 7) << 3));
                M1s[idx] = f2bf(m1);
                T1s[idx] = f2bf(t1);
                V1s[idx] = f2bf(v1);
            }
        }

    __syncthreads();

    // ---------------- Layer 2: m2/v2 moment GEMMs (K=256) ------------------
    // wave w owns cols [w*16, w*16+16) (1 N-tile), rows 0..31 (2 row-tiles)
    f32x4 m2a[2], v2a[2];
    #pragma unroll
    for (int rt = 0; rt < 2; ++rt) { m2a[rt] = (f32x4)0.f; v2a[rt] = (f32x4)0.f; }

    #pragma unroll
    for (int ks = 0; ks < 8; ++ks) {
        int f = w * 8 + ks;
        bf16x8 bmu = *(const bf16x8*)(ws + WS_W2MU  + (size_t)(f * 64 + lane) * 8);
        bf16x8 bvr = *(const bf16x8*)(ws + WS_W2VAR + (size_t)(f * 64 + lane) * 8);
        bf16x8 bsq = *(const bf16x8*)(ws + WS_W2SQ  + (size_t)(f * 64 + lane) * 8);
        #pragma unroll
        for (int rt = 0; rt < 2; ++rt) {
            int row  = rt * 16 + lrow;
            int base = row * 256 + ((ks * 32 + lk * 8) ^ ((row & 7) << 3));
            bf16x8 am = *(const bf16x8*)&M1s[base];
            bf16x8 at = *(const bf16x8*)&T1s[base];
            bf16x8 av = *(const bf16x8*)&V1s[base];
            m2a[rt] = __builtin_amdgcn_mfma_f32_16x16x32_bf16(am, bmu, m2a[rt], 0, 0, 0);
            v2a[rt] = __builtin_amdgcn_mfma_f32_16x16x32_bf16(at, bvr, v2a[rt], 0, 0, 0);
            v2a[rt] = __builtin_amdgcn_mfma_f32_16x16x32_bf16(av, bsq, v2a[rt], 0, 0, 0);
        }
    }

    // ---------------- Phase 3: precision-weighted scatter -------------------
    const int col = w * 16 + lrow;
    #pragma unroll
    for (int rt = 0; rt < 2; ++rt)
        #pragma unroll
        for (int i = 0; i < 4; ++i) {
            int grow = row0 + rt * 16 + lk * 4 + i;
            int gidx = Xidx[grow];
            float m2 = m2a[rt][i];
            float v2 = v2a[rt][i];
            float p  = 1.0f / (v2 + EPSF);
            atomicAdd(accP + (size_t)gidx * D1 + col, p);
            atomicAdd(accM + (size_t)gidx * D1 + col, p * m2);
        }
}

__global__ void dgp_finalize(float* __restrict__ accM,
                             float* __restrict__ accP, int total)
{
    int idx = blockIdx.x * blockDim.x + threadIdx.x;
    if (idx < total) {
        float var = 1.0f / (accP[idx] + EPSF);   // p_sum = seg_sum + EPS
        accP[idx] = var;                         // embedd_vars
        accM[idx] = accM[idx] * var;             // embedd_means
    }
}

extern "C" void kernel_launch(void* const* d_in, const int* in_sizes, int n_in,
                              void* d_out, int out_size, void* d_ws, size_t ws_size,
                              hipStream_t stream)
{
    const float* X     = (const float*)d_in[0];
    const int*   Xidx  = (const int*)d_in[1];
    const float* W1mu  = (const float*)d_in[2];
    const float* W1var = (const float*)d_in[3];
    const float* W2mu  = (const float*)d_in[4];
    const float* W2var = (const float*)d_in[5];

    const int N = in_sizes[0] / D0;            // 262144
    const int U = out_size / (2 * D1);         // 50000
    float* out  = (float*)d_out;
    float* accM = out;                          // means region
    float* accP = out + (size_t)U * D1;         // vars region
    ushort* ws  = (ushort*)d_ws;

    // harness does not re-poison between replays: re-zero accumulators
    hipMemsetAsync(d_out, 0, (size_t)out_size * sizeof(float), stream);

    convert_w<<<56, 256, 0, stream>>>(W1mu, W1var, W2mu, W2var, ws);

    dgp_mfma<<<N / BM, NT, 0, stream>>>(X, Xidx, ws, accM, accP);

    const int total = U * D1;
    dgp_finalize<<<(total + 255) / 256, 256, 0, stream>>>(accM, accP, total);
}